// Round 7
// baseline (260.322 us; speedup 1.0000x reference)
//
#include <hip/hip_runtime.h>

#define CDIM 512
#define NH 8
#define HWDIM 4096
#define TPOS 64     // positions per tile (one per lane)
#define NTILE 4     // tiles per block, pipelined
#define NT 512      // 8 waves

// Fold weights: wvT[c*8+n] = sum_j wqkv[(1024+64n+j)*512 + c]
//               wp [o*8+n] = sum_j wproj[o*512 + 64n + j]
__global__ __launch_bounds__(256) void prep_kernel(
    const float* __restrict__ wqkv, const float* __restrict__ wproj,
    float* __restrict__ wvT, float* __restrict__ wp) {
  int idx = blockIdx.x * 256 + threadIdx.x;
  if (idx < 4096) {
    int c = idx >> 3, n = idx & 7;
    const float* p = wqkv + (size_t)(1024 + n * 64) * CDIM + c;
    float s = 0.f;
#pragma unroll 8
    for (int j = 0; j < 64; ++j) s += p[(size_t)j * CDIM];
    wvT[idx] = s;
  } else if (idx < 8192) {
    int i2 = idx - 4096;
    int o = i2 >> 3, n = i2 & 7;
    const float* p = wproj + (size_t)o * CDIM + n * 64;
    float s = 0.f;
#pragma unroll 8
    for (int j = 0; j < 64; ++j) s += p[j];
    wp[i2] = s;
  }
}

// Pipelined fused kernel: block handles NTILE consecutive 64-pos tiles.
// Steady state interleaves stores(tile t-1) 1:1 with loads(tile t) so each CU
// issues reads AND writes continuously (breaks the device-wide read-phase /
// write-phase convoy that serialized 53us reads + 20us writes in R4/R6).
__global__ __launch_bounds__(NT, 1) void fused_kernel(
    const float* __restrict__ x, const float* __restrict__ bias,
    const float* __restrict__ wvT, const float* __restrict__ wp,
    float* __restrict__ y) {
  __shared__ __align__(16) float sWv[4096];            // [c][n]
  __shared__ __align__(16) float sWp[4096];            // [o][n]
  __shared__ __align__(16) float sB[512];
  __shared__ __align__(16) float sS[2][8][NH][TPOS];   // double-buffered partials

  const int t = threadIdx.x;
  for (int i = t; i < 4096; i += NT) { sWv[i] = wvT[i]; sWp[i] = wp[i]; }
  if (t < 512) sB[t] = bias[t];
  __syncthreads();

  const int wave = t >> 6;
  const int lane = t & 63;
  const int pos0 = blockIdx.x * (NTILE * TPOS);   // 256 | 4096: no b straddle
  const int b = pos0 >> 12;
  const int hw0 = pos0 & (HWDIM - 1);
  const float* xb = x + ((size_t)b * CDIM) * HWDIM + hw0 + lane;
  float* yb = y + ((size_t)b * CDIM) * HWDIM + hw0 + lane;

  const int g0 = wave * 64;                 // channel slice (p1) and output slice (p2)
  const int rot  = (blockIdx.x * 37) & 63;
  const int rot2 = (blockIdx.x * 23) & 63;

  float S2[NH];
  float acc[NH];

  // ---- prologue: tile 0 loads only ----
#pragma unroll
  for (int n = 0; n < NH; ++n) acc[n] = 0.f;
#pragma unroll 8
  for (int i = 0; i < 64; ++i) {
    const int c = g0 + ((i + rot) & 63);
    const float xv = xb[(size_t)c * HWDIM];
    const float4 w0 = *(const float4*)&sWv[c * 8];
    const float4 w1 = *(const float4*)&sWv[c * 8 + 4];
    acc[0] = fmaf(w0.x, xv, acc[0]); acc[1] = fmaf(w0.y, xv, acc[1]);
    acc[2] = fmaf(w0.z, xv, acc[2]); acc[3] = fmaf(w0.w, xv, acc[3]);
    acc[4] = fmaf(w1.x, xv, acc[4]); acc[5] = fmaf(w1.y, xv, acc[5]);
    acc[6] = fmaf(w1.z, xv, acc[6]); acc[7] = fmaf(w1.w, xv, acc[7]);
  }
#pragma unroll
  for (int n = 0; n < NH; ++n) sS[0][wave][n][lane] = acc[n];
  __syncthreads();
#pragma unroll
  for (int n = 0; n < NH; ++n) {
    float s = 0.f;
#pragma unroll
    for (int w = 0; w < 8; ++w) s += sS[0][w][n][lane];
    S2[n] = s;
  }

  // ---- steady state: stores(tile tt-1) interleaved with loads(tile tt) ----
  for (int tt = 1; tt < NTILE; ++tt) {
    const float* xbt = xb + tt * TPOS;
    float* ybp = yb + (tt - 1) * TPOS;
#pragma unroll
    for (int n = 0; n < NH; ++n) acc[n] = 0.f;
#pragma unroll 8
    for (int i = 0; i < 64; ++i) {
      // one store of previous tile
      const int o = g0 + ((i + rot2) & 63);
      const float4 p0 = *(const float4*)&sWp[o * 8];
      const float4 p1 = *(const float4*)&sWp[o * 8 + 4];
      float r = sB[o];
      r = fmaf(p0.x, S2[0], r); r = fmaf(p0.y, S2[1], r);
      r = fmaf(p0.z, S2[2], r); r = fmaf(p0.w, S2[3], r);
      r = fmaf(p1.x, S2[4], r); r = fmaf(p1.y, S2[5], r);
      r = fmaf(p1.z, S2[6], r); r = fmaf(p1.w, S2[7], r);
      __builtin_nontemporal_store(r, ybp + (size_t)o * HWDIM);
      // one load of current tile
      const int c = g0 + ((i + rot) & 63);
      const float xv = xbt[(size_t)c * HWDIM];
      const float4 w0 = *(const float4*)&sWv[c * 8];
      const float4 w1 = *(const float4*)&sWv[c * 8 + 4];
      acc[0] = fmaf(w0.x, xv, acc[0]); acc[1] = fmaf(w0.y, xv, acc[1]);
      acc[2] = fmaf(w0.z, xv, acc[2]); acc[3] = fmaf(w0.w, xv, acc[3]);
      acc[4] = fmaf(w1.x, xv, acc[4]); acc[5] = fmaf(w1.y, xv, acc[5]);
      acc[6] = fmaf(w1.z, xv, acc[6]); acc[7] = fmaf(w1.w, xv, acc[7]);
    }
    const int buf = tt & 1;
#pragma unroll
    for (int n = 0; n < NH; ++n) sS[buf][wave][n][lane] = acc[n];
    __syncthreads();
#pragma unroll
    for (int n = 0; n < NH; ++n) {
      float s = 0.f;
#pragma unroll
      for (int w = 0; w < 8; ++w) s += sS[buf][w][n][lane];
      S2[n] = s;
    }
  }

  // ---- epilogue: stores of last tile ----
  {
    float* ybp = yb + (NTILE - 1) * TPOS;
#pragma unroll 8
    for (int i = 0; i < 64; ++i) {
      const int o = g0 + ((i + rot2) & 63);
      const float4 p0 = *(const float4*)&sWp[o * 8];
      const float4 p1 = *(const float4*)&sWp[o * 8 + 4];
      float r = sB[o];
      r = fmaf(p0.x, S2[0], r); r = fmaf(p0.y, S2[1], r);
      r = fmaf(p0.z, S2[2], r); r = fmaf(p0.w, S2[3], r);
      r = fmaf(p1.x, S2[4], r); r = fmaf(p1.y, S2[5], r);
      r = fmaf(p1.z, S2[6], r); r = fmaf(p1.w, S2[7], r);
      __builtin_nontemporal_store(r, ybp + (size_t)o * HWDIM);
    }
  }
}

extern "C" void kernel_launch(void* const* d_in, const int* in_sizes, int n_in,
                              void* d_out, int out_size, void* d_ws, size_t ws_size,
                              hipStream_t stream) {
  const float* x     = (const float*)d_in[0];
  const float* wqkv  = (const float*)d_in[1];
  const float* wproj = (const float*)d_in[2];
  const float* bproj = (const float*)d_in[3];
  float* y = (float*)d_out;

  float* wvT = (float*)d_ws;        // 4096 floats
  float* wp  = wvT + 4096;          // 4096 floats (32 KB total scratch)

  prep_kernel<<<32, 256, 0, stream>>>(wqkv, wproj, wvT, wp);
  fused_kernel<<<(16 * HWDIM) / (NTILE * TPOS), NT, 0, stream>>>(x, bproj, wvT, wp, y);
}

// Round 8
// 245.325 us; speedup vs baseline: 1.0611x; 1.0611x over previous
//
#include <hip/hip_runtime.h>

#define CDIM 512
#define NH 8
#define HWDIM 4096
#define TILE 256   // spatial positions per block (lane owns float4)
#define NT 512     // 8 waves

typedef float f32x4 __attribute__((ext_vector_type(4)));

// Fold weights: wvT[c*8+n] = sum_j wqkv[(1024+64n+j)*512 + c]
//               wp [o*8+n] = sum_j wproj[o*512 + 64n + j]
__global__ __launch_bounds__(256) void prep_kernel(
    const float* __restrict__ wqkv, const float* __restrict__ wproj,
    float* __restrict__ wvT, float* __restrict__ wp) {
  int idx = blockIdx.x * 256 + threadIdx.x;
  if (idx < 4096) {
    int c = idx >> 3, n = idx & 7;
    const float* p = wqkv + (size_t)(1024 + n * 64) * CDIM + c;
    float s = 0.f;
#pragma unroll 8
    for (int j = 0; j < 64; ++j) s += p[(size_t)j * CDIM];
    wvT[idx] = s;
  } else if (idx < 8192) {
    int i2 = idx - 4096;
    int o = i2 >> 3, n = i2 & 7;
    const float* p = wproj + (size_t)o * CDIM + n * 64;
    float s = 0.f;
#pragma unroll 8
    for (int j = 0; j < 64; ++j) s += p[j];
    wp[i2] = s;
  }
}

// MLP experiment: lane owns float4 (1KB wave requests); phase 1 issues
// explicit 16-deep global_load_dwordx4 batches (16KB in flight per wave)
// before any consumption. 8 waves x 16KB = 128KB in flight per CU vs
// ~16-44KB in all prior rounds. Everything else matches R4's best kernel.
__global__ __launch_bounds__(NT, 1) void fused_kernel(
    const float* __restrict__ x, const float* __restrict__ bias,
    const float* __restrict__ wvT, const float* __restrict__ wp,
    float* __restrict__ y) {
  __shared__ __align__(16) float sWv[4096];            // [c][n]  16KB
  __shared__ __align__(16) float sWp[4096];            // [o][n]  16KB
  __shared__ __align__(16) float sB[512];              //          2KB
  __shared__ __align__(16) float sS[8][NH][TILE];      // partials 64KB

  const int t = threadIdx.x;
  for (int i = t; i < 4096; i += NT) { sWv[i] = wvT[i]; sWp[i] = wp[i]; }
  if (t < 512) sB[t] = bias[t];
  __syncthreads();

  const int wave = t >> 6;
  const int lane = t & 63;
  const int pos0 = blockIdx.x * TILE;        // 256 | 4096: no b straddle
  const int b = pos0 >> 12;
  const int hw0 = pos0 & (HWDIM - 1);
  const float* xb = x + ((size_t)b * CDIM) * HWDIM + hw0 + lane * 4;

  // ---- phase 1: wave owns 64 channels; 4 batches of 16-deep float4 loads ----
  float acc[NH][4];
#pragma unroll
  for (int n = 0; n < NH; ++n) { acc[n][0] = acc[n][1] = acc[n][2] = acc[n][3] = 0.f; }

  const int c0 = wave * 64;
  for (int g = 0; g < 4; ++g) {
    float4 xv[16];
#pragma unroll
    for (int j = 0; j < 16; ++j)
      xv[j] = *(const float4*)(xb + (size_t)(c0 + g * 16 + j) * HWDIM);
#pragma unroll
    for (int j = 0; j < 16; ++j) {
      const int c = c0 + g * 16 + j;
      const float4 w0 = *(const float4*)&sWv[c * 8];
      const float4 w1 = *(const float4*)&sWv[c * 8 + 4];
      const float wn[8] = {w0.x, w0.y, w0.z, w0.w, w1.x, w1.y, w1.z, w1.w};
      const float xr[4] = {xv[j].x, xv[j].y, xv[j].z, xv[j].w};
#pragma unroll
      for (int n = 0; n < NH; ++n) {
#pragma unroll
        for (int p = 0; p < 4; ++p) acc[n][p] = fmaf(wn[n], xr[p], acc[n][p]);
      }
    }
  }

#pragma unroll
  for (int n = 0; n < NH; ++n) {
    *(float4*)&sS[wave][n][lane * 4] =
        make_float4(acc[n][0], acc[n][1], acc[n][2], acc[n][3]);
  }
  __syncthreads();

  // ---- phase 2: reduce across 8 waves, expand to 512 outputs ----
  float S4[NH][4];
#pragma unroll
  for (int n = 0; n < NH; ++n) {
    float s0 = 0.f, s1 = 0.f, s2 = 0.f, s3 = 0.f;
#pragma unroll
    for (int w = 0; w < 8; ++w) {
      const float4 a = *(const float4*)&sS[w][n][lane * 4];
      s0 += a.x; s1 += a.y; s2 += a.z; s3 += a.w;
    }
    S4[n][0] = s0; S4[n][1] = s1; S4[n][2] = s2; S4[n][3] = s3;
  }

  float* yb = y + ((size_t)b * CDIM) * HWDIM + hw0 + lane * 4;
  const int o0 = wave * 64;
#pragma unroll 4
  for (int oo = 0; oo < 64; ++oo) {
    const int o = o0 + oo;
    const float4 w0 = *(const float4*)&sWp[o * 8];
    const float4 w1 = *(const float4*)&sWp[o * 8 + 4];
    const float wn[8] = {w0.x, w0.y, w0.z, w0.w, w1.x, w1.y, w1.z, w1.w};
    const float bb = sB[o];
    f32x4 r;
    r.x = bb; r.y = bb; r.z = bb; r.w = bb;
#pragma unroll
    for (int n = 0; n < NH; ++n) {
      r.x = fmaf(wn[n], S4[n][0], r.x);
      r.y = fmaf(wn[n], S4[n][1], r.y);
      r.z = fmaf(wn[n], S4[n][2], r.z);
      r.w = fmaf(wn[n], S4[n][3], r.w);
    }
    __builtin_nontemporal_store(r, (f32x4*)(yb + (size_t)o * HWDIM));
  }
}

extern "C" void kernel_launch(void* const* d_in, const int* in_sizes, int n_in,
                              void* d_out, int out_size, void* d_ws, size_t ws_size,
                              hipStream_t stream) {
  const float* x     = (const float*)d_in[0];
  const float* wqkv  = (const float*)d_in[1];
  const float* wproj = (const float*)d_in[2];
  const float* bproj = (const float*)d_in[3];
  float* y = (float*)d_out;

  float* wvT = (float*)d_ws;        // 4096 floats
  float* wp  = wvT + 4096;          // 4096 floats (32 KB total scratch)

  prep_kernel<<<32, 256, 0, stream>>>(wqkv, wproj, wvT, wp);
  fused_kernel<<<(16 * HWDIM) / TILE, NT, 0, stream>>>(x, bproj, wvT, wp, y);
}